// Round 8
// baseline (26.985 us; speedup 1.0000x reference)
//
#include <hip/hip_runtime.h>
#include <hip/hip_bf16.h>
#include <math.h>

#define NB 4
#define MA 256
#define NFS 128
#define KSEL 8
#define HID 256
#define NOUT 32
#define RCUT 5.0f
#define PI_F 3.14159265358979323846f

// Kernel 1: 1024 blocks = (rowgroup 0..255) x (PQ half) x (col half).
// Block computes 4 rows x 128 cols of (pq==0 ? P : Q) over f=0..127.
// Thread = (c = t&31 -> 4 cols, fq = t>>5 -> 16-f octant); LDS psum reduce.
__global__ __launch_bounds__(256) void prep_kernel(
    const int* __restrict__ z, const float* __restrict__ r,
    const float* __restrict__ h, const float* __restrict__ Wa,
    const float* __restrict__ Wp1,
    float* __restrict__ out,
    float* __restrict__ a1, float* __restrict__ a2,
    float* __restrict__ P, float* __restrict__ Q) {
  const int b = blockIdx.x;
  const int colhalf = b & 1;       // cols [128*colhalf, +128)
  const int pq = (b >> 1) & 1;     // 0 -> P, 1 -> Q
  const int rg = b >> 2;           // row group 0..255
  const int r0 = 4 * rg;
  const int t = threadIdx.x;       // 0..255
  const int wave = t >> 6, lane = t & 63;
  const int c = t & 31, fq = t >> 5;

  __shared__ __align__(16) float hsh[4][NFS];          // 2 KB
  __shared__ __align__(16) float psum[8][4][128];      // 16 KB

  ((float2*)hsh)[t] = ((const float2*)(h + (size_t)r0 * NFS))[t];
  __syncthreads();

  if (pq == 0 && colhalf == 0) {
    // a1/a2: wave w handles row r0+w
    const float h0 = hsh[wave][lane], h1 = hsh[wave][lane + 64];
    float p1 = h0 * Wa[lane]       + h1 * Wa[lane + 64];
    float p2 = h0 * Wa[NFS + lane] + h1 * Wa[NFS + lane + 64];
#pragma unroll
    for (int off = 32; off > 0; off >>= 1) {
      p1 += __shfl_down(p1, off);
      p2 += __shfl_down(p2, off);
    }
    if (lane == 0) { a1[r0 + wave] = p1; a2[r0 + wave] = p2; }
    if (t < 4)  out[r0 + t] = (float)z[r0 + t];
    if (t < 12) out[NB * MA + r0 * 3 + t] = r[r0 * 3 + t];
  }

  // partial GEMM: this thread's 16 f values, 4 rows x 4 cols
  const float* __restrict__ Wbase = Wp1 + (size_t)(pq ? NFS : 0) * HID + colhalf * 128;
  float4 acc[4] = {make_float4(0,0,0,0), make_float4(0,0,0,0),
                   make_float4(0,0,0,0), make_float4(0,0,0,0)};
#pragma unroll 4
  for (int ff = 0; ff < 16; ++ff) {
    const int f = fq * 16 + ff;
    const float4 w = *(const float4*)&Wbase[(size_t)f * HID + 4 * c];
#pragma unroll
    for (int rr = 0; rr < 4; ++rr) {
      const float hv = hsh[rr][f];     // LDS broadcast
      acc[rr].x = fmaf(hv, w.x, acc[rr].x);
      acc[rr].y = fmaf(hv, w.y, acc[rr].y);
      acc[rr].z = fmaf(hv, w.z, acc[rr].z);
      acc[rr].w = fmaf(hv, w.w, acc[rr].w);
    }
  }
#pragma unroll
  for (int rr = 0; rr < 4; ++rr) *(float4*)&psum[fq][rr][4 * c] = acc[rr];
  __syncthreads();

  // reduce over fq + store: thread -> (row = t>>6, local cols 2*c2, 2*c2+1)
  {
    const int r2 = t >> 6, c2 = t & 63;
    float2 s = *(const float2*)&psum[0][r2][2 * c2];
#pragma unroll
    for (int q = 1; q < 8; ++q) {
      const float2 p = *(const float2*)&psum[q][r2][2 * c2];
      s.x += p.x; s.y += p.y;
    }
    float* dst = (pq ? Q : P) + (size_t)(r0 + r2) * HID + colhalf * 128 + 2 * c2;
    *(float2*)dst = s;
  }
}

// Kernel 2: 2048 blocks = (row, khalf). g -> topk (4 or 8 rounds) ->
// hidden/layer2/store for the 4 local k.
__global__ __launch_bounds__(256) void main_kernel(
    const int* __restrict__ z, const float* __restrict__ r,
    const float* __restrict__ a1g, const float* __restrict__ a2g,
    const float* __restrict__ ba,
    const float* __restrict__ Pg, const float* __restrict__ Qg,
    const float* __restrict__ bp1,
    const float* __restrict__ Wp2g, const float* __restrict__ bp2,
    float* __restrict__ out) {
  const int row = blockIdx.x >> 1;      // n*MA + i
  const int khalf = blockIdx.x & 1;     // k in [4*khalf, 4*khalf+4)
  const int n = row >> 8;
  const int i = row & 255;
  const int tid = threadIdx.x;
  const int lane = tid & 63;

  __shared__ float gsh[MA];                       // 1 KB
  __shared__ __align__(16) float hid_sh[4][HID];  // 4 KB
  __shared__ float psum2[8][4][NOUT];             // 4 KB
  __shared__ int   idx_sh[4];

  // layer-2 roles; issue one-pass Wp2 loads EARLY (no dependencies)
  const int l2o = tid & 31;
  const int l2c = tid >> 5;
  float wreg[32];
#pragma unroll
  for (int j = 0; j < 32; ++j) wreg[j] = Wp2g[(size_t)(32 * l2c + j) * NOUT + l2o];

  // ---- g for all j (this thread's j = tid) ----
  const float rix = r[row * 3 + 0], riy = r[row * 3 + 1], riz = r[row * 3 + 2];
  {
    const int jg = n * MA + tid;
    const float dx = r[jg * 3 + 0] - rix;
    const float dy = r[jg * 3 + 1] - riy;
    const float dz = r[jg * 3 + 2] - riz;
    const float d = sqrtf(dx * dx + dy * dy + dz * dz);
    const int mi = (z[row] > -1) ? 1 : 0;
    const int mj = (z[jg] > -1) ? 1 : 0;
    const int mask = max(mi * mj - ((tid == i) ? 1 : 0), 0);
    float g = 0.0f;
    if (mask) {
      const float cf = 0.5f * (__cosf(PI_F * fminf(d, RCUT) / RCUT) + 1.0f);
      g = __expf(a1g[row] + cf * a2g[jg] + ba[0]);
    }
    gsh[tid] = g;
  }
  __syncthreads();

  // ---- ALL waves: denom + topk via shfl; this block keeps ranks [4k..4k+4) ----
  float att4[4];
  int   idx4[4];
  {
    float v0 = gsh[lane];
    float v1 = gsh[lane + 64];
    float v2 = gsh[lane + 128];
    float v3 = gsh[lane + 192];
    float s = (v0 + v1) + (v2 + v3);
#pragma unroll
    for (int off = 32; off > 0; off >>= 1) s += __shfl_xor(s, off);
    const float rden = 1.0f / fmaxf(s, 1e-8f);
#pragma unroll
    for (int k = 0; k < KSEL; k++) {
      if (k < 4 || khalf == 1) {           // khalf==0 blocks stop after 4 rounds
        float bv = v0; int bi = lane;
        if (v1 > bv) { bv = v1; bi = lane + 64; }
        if (v2 > bv) { bv = v2; bi = lane + 128; }
        if (v3 > bv) { bv = v3; bi = lane + 192; }
#pragma unroll
        for (int off = 32; off > 0; off >>= 1) {
          const float ov = __shfl_xor(bv, off);
          const int oi = __shfl_xor(bi, off);
          if (ov > bv || (ov == bv && oi < bi)) { bv = ov; bi = oi; }
        }
        if ((k >> 2) == khalf) {           // static k&3 index
          att4[k & 3] = bv * rden;
          idx4[k & 3] = __builtin_amdgcn_readfirstlane(bi);
        }
        const int slot = bi >> 6, who = bi & 63;
        if (lane == who) {
          if (slot == 0) v0 = -1.0f;
          else if (slot == 1) v1 = -1.0f;
          else if (slot == 2) v2 = -1.0f;
          else v3 = -1.0f;
        }
      }
    }
  }
  // publish idx for the final phase (all waves write identical values)
  if (lane == 0) {
    idx_sh[0] = idx4[0]; idx_sh[1] = idx4[1];
    idx_sh[2] = idx4[2]; idx_sh[3] = idx4[3];
  }

  // ---- hidden: hid[k][tid] = silu(att_k*(P[i][tid]+Q[jk][tid]) + bp1[tid]) ----
  {
    const float pi = Pg[(size_t)row * HID + tid];
    const float bb = bp1[tid];
#pragma unroll
    for (int k = 0; k < 4; k++) {
      const float q = Qg[(size_t)(n * MA + idx4[k]) * HID + tid];
      const float x = att4[k] * (pi + q) + bb;
      hid_sh[k][tid] = x / (1.0f + __expf(-x));
    }
  }
  __syncthreads();

  // ---- layer 2, broadcast scheme: thread (o=l2o, chunk=l2c) ----
  {
    float acc[4];
#pragma unroll
    for (int k = 0; k < 4; ++k) acc[k] = 0.0f;
#pragma unroll
    for (int k = 0; k < 4; ++k) {
      const float4* __restrict__ hrow = (const float4*)&hid_sh[k][32 * l2c];
#pragma unroll
      for (int j4 = 0; j4 < 8; ++j4) {
        const float4 hv = hrow[j4];    // uniform across 32-lane group -> broadcast
        acc[k] = fmaf(hv.x, wreg[4 * j4 + 0],
                 fmaf(hv.y, wreg[4 * j4 + 1],
                 fmaf(hv.z, wreg[4 * j4 + 2],
                 fmaf(hv.w, wreg[4 * j4 + 3], acc[k]))));
      }
    }
#pragma unroll
    for (int k = 0; k < 4; ++k) psum2[l2c][k][l2o] = acc[k];
  }
  __syncthreads();

  // ---- final: threads 0..127: (k2 = tid>>5, o = tid&31); dvk inline ----
  if (tid < 128) {
    const int k2 = tid >> 5;
    const int o = tid & 31;
    float s = bp2[o];
#pragma unroll
    for (int cc = 0; cc < 8; ++cc) s += psum2[cc][k2][o];
    const int jg = n * MA + idx_sh[k2];
    const float dx = r[jg * 3 + 0] - rix;
    const float dy = r[jg * 3 + 1] - riy;
    const float dz = r[jg * 3 + 2] - riz;
    const float nrm = fmaxf(sqrtf(dx * dx + dy * dy + dz * dz), 1e-4f);
    float* cb = out + NB * MA + NB * MA * 3 +
                ((size_t)row * KSEL + 4 * khalf + k2) * (NOUT * 3) + o * 3;
    cb[0] = s * (dx / nrm);
    cb[1] = s * (dy / nrm);
    cb[2] = s * (dz / nrm);
  }
}

extern "C" void kernel_launch(void* const* d_in, const int* in_sizes, int n_in,
                              void* d_out, int out_size, void* d_ws, size_t ws_size,
                              hipStream_t stream) {
  const int*   z   = (const int*)d_in[0];
  const float* r   = (const float*)d_in[1];
  const float* h   = (const float*)d_in[2];
  const float* Wa  = (const float*)d_in[3];
  const float* ba  = (const float*)d_in[4];
  const float* Wp1 = (const float*)d_in[5];
  const float* bp1 = (const float*)d_in[6];
  const float* Wp2 = (const float*)d_in[7];
  const float* bp2 = (const float*)d_in[8];
  float* out = (float*)d_out;

  float* a1 = (float*)d_ws;                 // 1024
  float* a2 = a1 + NB * MA;                 // 1024
  float* P  = a2 + NB * MA;                 // 1024*256
  float* Q  = P + (size_t)NB * MA * HID;    // 1024*256

  prep_kernel<<<4 * (NB * MA / 4), 256, 0, stream>>>(z, r, h, Wa, Wp1, out, a1, a2, P, Q);
  main_kernel<<<2 * NB * MA, 256, 0, stream>>>(z, r, a1, a2, ba, P, Q, bp1, Wp2, bp2, out);
}

// Round 9
// 26.729 us; speedup vs baseline: 1.0096x; 1.0096x over previous
//
#include <hip/hip_runtime.h>
#include <hip/hip_bf16.h>
#include <math.h>

#define NB 4
#define MA 256
#define NFS 128
#define KSEL 8
#define HID 256
#define NOUT 32
#define RCUT 5.0f
#define PI_F 3.14159265358979323846f

// Kernel 1: 512 blocks = (rowgroup 0..255) x (half 0..1).
// Block computes 4 rows x 256 cols of (half==0 ? P : Q) over full f=0..127.
__global__ __launch_bounds__(256) void prep_kernel(
    const int* __restrict__ z, const float* __restrict__ r,
    const float* __restrict__ h, const float* __restrict__ Wa,
    const float* __restrict__ Wp1,
    float* __restrict__ out,
    float* __restrict__ a1, float* __restrict__ a2,
    float* __restrict__ P, float* __restrict__ Q) {
  const int b = blockIdx.x;
  const int half = b & 1;
  const int rg = b >> 1;
  const int r0 = 4 * rg;
  const int t = threadIdx.x;
  const int wave = t >> 6, lane = t & 63;
  const int c = t & 63, fq = t >> 6;

  __shared__ __align__(16) float hsh[4][NFS];
  __shared__ __align__(16) float psum[4][4][HID];   // 16 KB

  ((float2*)hsh)[t] = ((const float2*)(h + (size_t)r0 * NFS))[t];
  __syncthreads();

  if (half == 0) {
    const float h0 = hsh[wave][lane], h1 = hsh[wave][lane + 64];
    float p1 = h0 * Wa[lane]       + h1 * Wa[lane + 64];
    float p2 = h0 * Wa[NFS + lane] + h1 * Wa[NFS + lane + 64];
#pragma unroll
    for (int off = 32; off > 0; off >>= 1) {
      p1 += __shfl_down(p1, off);
      p2 += __shfl_down(p2, off);
    }
    if (lane == 0) { a1[r0 + wave] = p1; a2[r0 + wave] = p2; }
    if (t < 4)  out[r0 + t] = (float)z[r0 + t];
    if (t < 12) out[NB * MA + r0 * 3 + t] = r[r0 * 3 + t];
  }

  const float* __restrict__ Wbase = Wp1 + (size_t)(half ? NFS : 0) * HID;
  float4 acc[4] = {make_float4(0,0,0,0), make_float4(0,0,0,0),
                   make_float4(0,0,0,0), make_float4(0,0,0,0)};
#pragma unroll 4
  for (int ff = 0; ff < 32; ++ff) {
    const int f = fq * 32 + ff;
    const float4 w = *(const float4*)&Wbase[(size_t)f * HID + 4 * c];
#pragma unroll
    for (int rr = 0; rr < 4; ++rr) {
      const float hv = hsh[rr][f];
      acc[rr].x = fmaf(hv, w.x, acc[rr].x);
      acc[rr].y = fmaf(hv, w.y, acc[rr].y);
      acc[rr].z = fmaf(hv, w.z, acc[rr].z);
      acc[rr].w = fmaf(hv, w.w, acc[rr].w);
    }
  }
#pragma unroll
  for (int rr = 0; rr < 4; ++rr) *(float4*)&psum[fq][rr][4 * c] = acc[rr];
  __syncthreads();

  {
    const int r2 = t >> 6, c2 = t & 63;
    float4 s = *(const float4*)&psum[0][r2][4 * c2];
#pragma unroll
    for (int q = 1; q < 4; ++q) {
      const float4 p = *(const float4*)&psum[q][r2][4 * c2];
      s.x += p.x; s.y += p.y; s.z += p.z; s.w += p.w;
    }
    float* dst = (half ? Q : P) + (size_t)(r0 + r2) * HID + 4 * c2;
    *(float4*)dst = s;
  }
}

// Kernel 2: 512 blocks, 2 rows per block. Interleaved g/topk chains; shared wreg;
// hidden + layer2 + store for both rows.
__global__ __launch_bounds__(256) void main_kernel(
    const int* __restrict__ z, const float* __restrict__ r,
    const float* __restrict__ a1g, const float* __restrict__ a2g,
    const float* __restrict__ ba,
    const float* __restrict__ Pg, const float* __restrict__ Qg,
    const float* __restrict__ bp1,
    const float* __restrict__ Wp2g, const float* __restrict__ bp2,
    float* __restrict__ out) {
  const int rowA = blockIdx.x * 2;      // rows rowA, rowA+1 (same batch: MA=256 even)
  const int rowB = rowA + 1;
  const int n = rowA >> 8;
  const int iA = rowA & 255, iB = rowB & 255;
  const int tid = threadIdx.x;
  const int lane = tid & 63;

  __shared__ float gsh[2][MA];                        // 2 KB
  __shared__ __align__(16) float hid_sh[2][KSEL][HID]; // 16 KB
  __shared__ float psum2[2][8][KSEL][NOUT];            // 16 KB
  __shared__ int   idx_sh[2][KSEL];

  // layer-2 roles; one-pass Wp2 loads issued EARLY, shared by both rows
  const int l2o = tid & 31;
  const int l2c = tid >> 5;
  float wreg[32];
#pragma unroll
  for (int j = 0; j < 32; ++j) wreg[j] = Wp2g[(size_t)(32 * l2c + j) * NOUT + l2o];

  // ---- g for both rows (shared r[jg] gather) ----
  const float rAx = r[rowA * 3 + 0], rAy = r[rowA * 3 + 1], rAz = r[rowA * 3 + 2];
  const float rBx = r[rowB * 3 + 0], rBy = r[rowB * 3 + 1], rBz = r[rowB * 3 + 2];
  {
    const int jg = n * MA + tid;
    const float rjx = r[jg * 3 + 0], rjy = r[jg * 3 + 1], rjz = r[jg * 3 + 2];
    const int mj = (z[jg] > -1) ? 1 : 0;
    const int miA = (z[rowA] > -1) ? 1 : 0;
    const int miB = (z[rowB] > -1) ? 1 : 0;
    const float a2j = a2g[jg];
    const float ba0 = ba[0];

    const float dxA = rjx - rAx, dyA = rjy - rAy, dzA = rjz - rAz;
    const float dA = sqrtf(dxA * dxA + dyA * dyA + dzA * dzA);
    const int maskA = max(miA * mj - ((tid == iA) ? 1 : 0), 0);
    float gA = 0.0f;
    if (maskA) {
      const float cf = 0.5f * (__cosf(PI_F * fminf(dA, RCUT) / RCUT) + 1.0f);
      gA = __expf(a1g[rowA] + cf * a2j + ba0);
    }
    gsh[0][tid] = gA;

    const float dxB = rjx - rBx, dyB = rjy - rBy, dzB = rjz - rBz;
    const float dB = sqrtf(dxB * dxB + dyB * dyB + dzB * dzB);
    const int maskB = max(miB * mj - ((tid == iB) ? 1 : 0), 0);
    float gB = 0.0f;
    if (maskB) {
      const float cf = 0.5f * (__cosf(PI_F * fminf(dB, RCUT) / RCUT) + 1.0f);
      gB = __expf(a1g[rowB] + cf * a2j + ba0);
    }
    gsh[1][tid] = gB;
  }
  __syncthreads();

  // ---- ALL waves: two interleaved denom+top-8 chains ----
  float attA[KSEL], attB[KSEL];
  int   idxA[KSEL], idxB[KSEL];
  {
    float v0A = gsh[0][lane],       v0B = gsh[1][lane];
    float v1A = gsh[0][lane + 64],  v1B = gsh[1][lane + 64];
    float v2A = gsh[0][lane + 128], v2B = gsh[1][lane + 128];
    float v3A = gsh[0][lane + 192], v3B = gsh[1][lane + 192];
    float sA = (v0A + v1A) + (v2A + v3A);
    float sB = (v0B + v1B) + (v2B + v3B);
#pragma unroll
    for (int off = 32; off > 0; off >>= 1) {
      sA += __shfl_xor(sA, off);
      sB += __shfl_xor(sB, off);
    }
    const float rdenA = 1.0f / fmaxf(sA, 1e-8f);
    const float rdenB = 1.0f / fmaxf(sB, 1e-8f);
#pragma unroll
    for (int k = 0; k < KSEL; k++) {
      float bvA = v0A; int biA = lane;
      if (v1A > bvA) { bvA = v1A; biA = lane + 64; }
      if (v2A > bvA) { bvA = v2A; biA = lane + 128; }
      if (v3A > bvA) { bvA = v3A; biA = lane + 192; }
      float bvB = v0B; int biB = lane;
      if (v1B > bvB) { bvB = v1B; biB = lane + 64; }
      if (v2B > bvB) { bvB = v2B; biB = lane + 128; }
      if (v3B > bvB) { bvB = v3B; biB = lane + 192; }
#pragma unroll
      for (int off = 32; off > 0; off >>= 1) {
        const float ovA = __shfl_xor(bvA, off);
        const int   oiA = __shfl_xor(biA, off);
        const float ovB = __shfl_xor(bvB, off);
        const int   oiB = __shfl_xor(biB, off);
        if (ovA > bvA || (ovA == bvA && oiA < biA)) { bvA = ovA; biA = oiA; }
        if (ovB > bvB || (ovB == bvB && oiB < biB)) { bvB = ovB; biB = oiB; }
      }
      attA[k] = bvA * rdenA;
      idxA[k] = __builtin_amdgcn_readfirstlane(biA);
      attB[k] = bvB * rdenB;
      idxB[k] = __builtin_amdgcn_readfirstlane(biB);
      {
        const int slot = biA >> 6, who = biA & 63;
        if (lane == who) {
          if (slot == 0) v0A = -1.0f;
          else if (slot == 1) v1A = -1.0f;
          else if (slot == 2) v2A = -1.0f;
          else v3A = -1.0f;
        }
      }
      {
        const int slot = biB >> 6, who = biB & 63;
        if (lane == who) {
          if (slot == 0) v0B = -1.0f;
          else if (slot == 1) v1B = -1.0f;
          else if (slot == 2) v2B = -1.0f;
          else v3B = -1.0f;
        }
      }
    }
  }
  if (lane == 0) {
#pragma unroll
    for (int k = 0; k < KSEL; ++k) { idx_sh[0][k] = idxA[k]; idx_sh[1][k] = idxB[k]; }
  }

  // ---- hidden for both rows ----
  {
    const float pA = Pg[(size_t)rowA * HID + tid];
    const float pB = Pg[(size_t)rowB * HID + tid];
    const float bb = bp1[tid];
#pragma unroll
    for (int k = 0; k < KSEL; k++) {
      const float qA = Qg[(size_t)(n * MA + idxA[k]) * HID + tid];
      const float xA = attA[k] * (pA + qA) + bb;
      hid_sh[0][k][tid] = xA / (1.0f + __expf(-xA));
      const float qB = Qg[(size_t)(n * MA + idxB[k]) * HID + tid];
      const float xB = attB[k] * (pB + qB) + bb;
      hid_sh[1][k][tid] = xB / (1.0f + __expf(-xB));
    }
  }
  __syncthreads();

  // ---- layer 2, broadcast scheme, both rows ----
  {
#pragma unroll
    for (int rr = 0; rr < 2; ++rr) {
      float acc[KSEL];
#pragma unroll
      for (int k = 0; k < KSEL; ++k) acc[k] = 0.0f;
#pragma unroll
      for (int k = 0; k < KSEL; ++k) {
        const float4* __restrict__ hrow = (const float4*)&hid_sh[rr][k][32 * l2c];
#pragma unroll
        for (int j4 = 0; j4 < 8; ++j4) {
          const float4 hv = hrow[j4];
          acc[k] = fmaf(hv.x, wreg[4 * j4 + 0],
                   fmaf(hv.y, wreg[4 * j4 + 1],
                   fmaf(hv.z, wreg[4 * j4 + 2],
                   fmaf(hv.w, wreg[4 * j4 + 3], acc[k]))));
        }
      }
#pragma unroll
      for (int k = 0; k < KSEL; ++k) psum2[rr][l2c][k][l2o] = acc[k];
    }
  }
  __syncthreads();

  // ---- final: thread (k2 = tid>>5, o = tid&31) handles both rows ----
  {
    const int k2 = tid >> 5;
    const int o = tid & 31;
#pragma unroll
    for (int rr = 0; rr < 2; ++rr) {
      float s = bp2[o];
#pragma unroll
      for (int cc = 0; cc < 8; ++cc) s += psum2[rr][cc][k2][o];
      const int jg = n * MA + idx_sh[rr][k2];
      const float rix = rr ? rBx : rAx;
      const float riy = rr ? rBy : rAy;
      const float riz = rr ? rBz : rAz;
      const float dx = r[jg * 3 + 0] - rix;
      const float dy = r[jg * 3 + 1] - riy;
      const float dz = r[jg * 3 + 2] - riz;
      const float nrm = fmaxf(sqrtf(dx * dx + dy * dy + dz * dz), 1e-4f);
      float* cb = out + NB * MA + NB * MA * 3 +
                  ((size_t)(rowA + rr) * KSEL + k2) * (NOUT * 3) + o * 3;
      cb[0] = s * (dx / nrm);
      cb[1] = s * (dy / nrm);
      cb[2] = s * (dz / nrm);
    }
  }
}

extern "C" void kernel_launch(void* const* d_in, const int* in_sizes, int n_in,
                              void* d_out, int out_size, void* d_ws, size_t ws_size,
                              hipStream_t stream) {
  const int*   z   = (const int*)d_in[0];
  const float* r   = (const float*)d_in[1];
  const float* h   = (const float*)d_in[2];
  const float* Wa  = (const float*)d_in[3];
  const float* ba  = (const float*)d_in[4];
  const float* Wp1 = (const float*)d_in[5];
  const float* bp1 = (const float*)d_in[6];
  const float* Wp2 = (const float*)d_in[7];
  const float* bp2 = (const float*)d_in[8];
  float* out = (float*)d_out;

  float* a1 = (float*)d_ws;                 // 1024
  float* a2 = a1 + NB * MA;                 // 1024
  float* P  = a2 + NB * MA;                 // 1024*256
  float* Q  = P + (size_t)NB * MA * HID;    // 1024*256

  prep_kernel<<<2 * NB * MA / 4, 256, 0, stream>>>(z, r, h, Wa, Wp1, out, a1, a2, P, Q);
  main_kernel<<<NB * MA / 2, 256, 0, stream>>>(z, r, a1, a2, ba, P, Q, bp1, Wp2, bp2, out);
}

// Round 10
// 23.739 us; speedup vs baseline: 1.1367x; 1.1260x over previous
//
#include <hip/hip_runtime.h>
#include <hip/hip_bf16.h>
#include <math.h>

#define NB 4
#define MA 256
#define NFS 128
#define KSEL 8
#define HID 256
#define NOUT 32
#define RCUT 5.0f
#define PI_F 3.14159265358979323846f

// Kernel 1: 512 blocks = (rowgroup 0..255) x (half 0..1).
// Block computes 4 rows x 256 cols of (half==0 ? P : Q) over full f=0..127.
__global__ __launch_bounds__(256) void prep_kernel(
    const int* __restrict__ z, const float* __restrict__ r,
    const float* __restrict__ h, const float* __restrict__ Wa,
    const float* __restrict__ Wp1,
    float* __restrict__ out,
    float* __restrict__ a1, float* __restrict__ a2,
    float* __restrict__ P, float* __restrict__ Q) {
  const int b = blockIdx.x;
  const int half = b & 1;
  const int rg = b >> 1;
  const int r0 = 4 * rg;
  const int t = threadIdx.x;
  const int wave = t >> 6, lane = t & 63;
  const int c = t & 63, fq = t >> 6;

  __shared__ __align__(16) float hsh[4][NFS];
  __shared__ __align__(16) float psum[4][4][HID];   // 16 KB

  ((float2*)hsh)[t] = ((const float2*)(h + (size_t)r0 * NFS))[t];
  __syncthreads();

  if (half == 0) {
    const float h0 = hsh[wave][lane], h1 = hsh[wave][lane + 64];
    float p1 = h0 * Wa[lane]       + h1 * Wa[lane + 64];
    float p2 = h0 * Wa[NFS + lane] + h1 * Wa[NFS + lane + 64];
#pragma unroll
    for (int off = 32; off > 0; off >>= 1) {
      p1 += __shfl_down(p1, off);
      p2 += __shfl_down(p2, off);
    }
    if (lane == 0) { a1[r0 + wave] = p1; a2[r0 + wave] = p2; }
    if (t < 4)  out[r0 + t] = (float)z[r0 + t];
    if (t < 12) out[NB * MA + r0 * 3 + t] = r[r0 * 3 + t];
  }

  const float* __restrict__ Wbase = Wp1 + (size_t)(half ? NFS : 0) * HID;
  float4 acc[4] = {make_float4(0,0,0,0), make_float4(0,0,0,0),
                   make_float4(0,0,0,0), make_float4(0,0,0,0)};
#pragma unroll 4
  for (int ff = 0; ff < 32; ++ff) {
    const int f = fq * 32 + ff;
    const float4 w = *(const float4*)&Wbase[(size_t)f * HID + 4 * c];
#pragma unroll
    for (int rr = 0; rr < 4; ++rr) {
      const float hv = hsh[rr][f];
      acc[rr].x = fmaf(hv, w.x, acc[rr].x);
      acc[rr].y = fmaf(hv, w.y, acc[rr].y);
      acc[rr].z = fmaf(hv, w.z, acc[rr].z);
      acc[rr].w = fmaf(hv, w.w, acc[rr].w);
    }
  }
#pragma unroll
  for (int rr = 0; rr < 4; ++rr) *(float4*)&psum[fq][rr][4 * c] = acc[rr];
  __syncthreads();

  {
    const int r2 = t >> 6, c2 = t & 63;
    float4 s = *(const float4*)&psum[0][r2][4 * c2];
#pragma unroll
    for (int q = 1; q < 4; ++q) {
      const float4 p = *(const float4*)&psum[q][r2][4 * c2];
      s.x += p.x; s.y += p.y; s.z += p.z; s.w += p.w;
    }
    float* dst = (half ? Q : P) + (size_t)(r0 + r2) * HID + 4 * c2;
    *(float4*)dst = s;
  }
}

// Kernel 2: 1024 blocks, one per row. g -> denom+top8 (wave 0) -> write att/idx to ws.
__global__ __launch_bounds__(256) void topk_kernel(
    const int* __restrict__ z, const float* __restrict__ r,
    const float* __restrict__ a1g, const float* __restrict__ a2g,
    const float* __restrict__ ba,
    float* __restrict__ attw, int* __restrict__ idxw) {
  const int row = blockIdx.x;   // n*MA + i
  const int n = row >> 8;
  const int i = row & 255;
  const int tid = threadIdx.x;
  const int lane = tid & 63;
  const int wave = tid >> 6;

  __shared__ float gsh[MA];

  // ---- g for all j (this thread's j = tid) ----
  const float rix = r[row * 3 + 0], riy = r[row * 3 + 1], riz = r[row * 3 + 2];
  {
    const int jg = n * MA + tid;
    const float dx = r[jg * 3 + 0] - rix;
    const float dy = r[jg * 3 + 1] - riy;
    const float dz = r[jg * 3 + 2] - riz;
    const float d = sqrtf(dx * dx + dy * dy + dz * dz);
    const int mi = (z[row] > -1) ? 1 : 0;
    const int mj = (z[jg] > -1) ? 1 : 0;
    const int mask = max(mi * mj - ((tid == i) ? 1 : 0), 0);
    float g = 0.0f;
    if (mask) {
      const float cf = 0.5f * (__cosf(PI_F * fminf(d, RCUT) / RCUT) + 1.0f);
      g = __expf(a1g[row] + cf * a2g[jg] + ba[0]);
    }
    gsh[tid] = g;
  }
  __syncthreads();
  if (wave != 0) return;

  // ---- wave 0: denom + top-8 via shfl ----
  float att[KSEL];
  int   idx[KSEL];
  {
    float v0 = gsh[lane];
    float v1 = gsh[lane + 64];
    float v2 = gsh[lane + 128];
    float v3 = gsh[lane + 192];
    float s = (v0 + v1) + (v2 + v3);
#pragma unroll
    for (int off = 32; off > 0; off >>= 1) s += __shfl_xor(s, off);
    const float rden = 1.0f / fmaxf(s, 1e-8f);
#pragma unroll
    for (int k = 0; k < KSEL; k++) {
      float bv = v0; int bi = lane;
      if (v1 > bv) { bv = v1; bi = lane + 64; }
      if (v2 > bv) { bv = v2; bi = lane + 128; }
      if (v3 > bv) { bv = v3; bi = lane + 192; }
#pragma unroll
      for (int off = 32; off > 0; off >>= 1) {
        const float ov = __shfl_xor(bv, off);
        const int oi = __shfl_xor(bi, off);
        if (ov > bv || (ov == bv && oi < bi)) { bv = ov; bi = oi; }
      }
      att[k] = bv * rden;
      idx[k] = __builtin_amdgcn_readfirstlane(bi);
      const int slot = bi >> 6, who = bi & 63;
      if (lane == who) {
        if (slot == 0) v0 = -1.0f;
        else if (slot == 1) v1 = -1.0f;
        else if (slot == 2) v2 = -1.0f;
        else v3 = -1.0f;
      }
    }
  }
  if (lane == 0) {
#pragma unroll
    for (int k = 0; k < KSEL; ++k) {
      attw[row * KSEL + k] = att[k];
      idxw[row * KSEL + k] = idx[k];
    }
  }
}

// Kernel 3: 2048 blocks = (row, khalf). hidden + layer2 + store for 4 k.
// LDS 8.2 KB -> 8 blocks/CU (full 32-wave occupancy).
__global__ __launch_bounds__(256) void mlp_kernel(
    const float* __restrict__ r,
    const float* __restrict__ Pg, const float* __restrict__ Qg,
    const float* __restrict__ bp1,
    const float* __restrict__ Wp2g, const float* __restrict__ bp2,
    const float* __restrict__ attw, const int* __restrict__ idxw,
    float* __restrict__ out) {
  const int row = blockIdx.x >> 1;      // n*MA + i
  const int khalf = blockIdx.x & 1;     // k in [4*khalf, 4*khalf+4)
  const int n = row >> 8;
  const int tid = threadIdx.x;

  __shared__ __align__(16) float hid_sh[4][HID];  // 4 KB
  __shared__ float psum2[8][4][NOUT];             // 4 KB

  // att/idx for this block's 4 ranks (uniform loads)
  float att4[4]; int idx4[4];
#pragma unroll
  for (int k = 0; k < 4; ++k) {
    att4[k] = attw[row * KSEL + 4 * khalf + k];
    idx4[k] = idxw[row * KSEL + 4 * khalf + k];
  }

  // one-pass Wp2 staging into registers
  const int l2o = tid & 31;
  const int l2c = tid >> 5;
  float wreg[32];
#pragma unroll
  for (int j = 0; j < 32; ++j) wreg[j] = Wp2g[(size_t)(32 * l2c + j) * NOUT + l2o];

  // ---- hidden: hid[k][tid] = silu(att_k*(P[i][tid]+Q[jk][tid]) + bp1[tid]) ----
  {
    const float pi = Pg[(size_t)row * HID + tid];
    const float bb = bp1[tid];
#pragma unroll
    for (int k = 0; k < 4; k++) {
      const float q = Qg[(size_t)(n * MA + idx4[k]) * HID + tid];
      const float x = att4[k] * (pi + q) + bb;
      hid_sh[k][tid] = x / (1.0f + __expf(-x));
    }
  }
  __syncthreads();

  // ---- layer 2, broadcast scheme: thread (o=l2o, chunk=l2c) ----
  {
    float acc[4];
#pragma unroll
    for (int k = 0; k < 4; ++k) acc[k] = 0.0f;
#pragma unroll
    for (int k = 0; k < 4; ++k) {
      const float4* __restrict__ hrow = (const float4*)&hid_sh[k][32 * l2c];
#pragma unroll
      for (int j4 = 0; j4 < 8; ++j4) {
        const float4 hv = hrow[j4];    // uniform across 32-lane group -> broadcast
        acc[k] = fmaf(hv.x, wreg[4 * j4 + 0],
                 fmaf(hv.y, wreg[4 * j4 + 1],
                 fmaf(hv.z, wreg[4 * j4 + 2],
                 fmaf(hv.w, wreg[4 * j4 + 3], acc[k]))));
      }
    }
#pragma unroll
    for (int k = 0; k < 4; ++k) psum2[l2c][k][l2o] = acc[k];
  }
  __syncthreads();

  // ---- final: threads 0..127: (k2 = tid>>5, o = tid&31); dvk inline ----
  if (tid < 128) {
    const int k2 = tid >> 5;
    const int o = tid & 31;
    float s = bp2[o];
#pragma unroll
    for (int cc = 0; cc < 8; ++cc) s += psum2[cc][k2][o];
    const float rix = r[row * 3 + 0], riy = r[row * 3 + 1], riz = r[row * 3 + 2];
    const int jg = n * MA + idx4[k2];
    const float dx = r[jg * 3 + 0] - rix;
    const float dy = r[jg * 3 + 1] - riy;
    const float dz = r[jg * 3 + 2] - riz;
    const float nrm = fmaxf(sqrtf(dx * dx + dy * dy + dz * dz), 1e-4f);
    float* cb = out + NB * MA + NB * MA * 3 +
                ((size_t)row * KSEL + 4 * khalf + k2) * (NOUT * 3) + o * 3;
    cb[0] = s * (dx / nrm);
    cb[1] = s * (dy / nrm);
    cb[2] = s * (dz / nrm);
  }
}

extern "C" void kernel_launch(void* const* d_in, const int* in_sizes, int n_in,
                              void* d_out, int out_size, void* d_ws, size_t ws_size,
                              hipStream_t stream) {
  const int*   z   = (const int*)d_in[0];
  const float* r   = (const float*)d_in[1];
  const float* h   = (const float*)d_in[2];
  const float* Wa  = (const float*)d_in[3];
  const float* ba  = (const float*)d_in[4];
  const float* Wp1 = (const float*)d_in[5];
  const float* bp1 = (const float*)d_in[6];
  const float* Wp2 = (const float*)d_in[7];
  const float* bp2 = (const float*)d_in[8];
  float* out = (float*)d_out;

  float* a1   = (float*)d_ws;                  // 1024
  float* a2   = a1 + NB * MA;                  // 1024
  float* P    = a2 + NB * MA;                  // 1024*256
  float* Q    = P + (size_t)NB * MA * HID;     // 1024*256
  float* attw = Q + (size_t)NB * MA * HID;     // 1024*8
  int*   idxw = (int*)(attw + NB * MA * KSEL); // 1024*8

  prep_kernel<<<2 * NB * MA / 4, 256, 0, stream>>>(z, r, h, Wa, Wp1, out, a1, a2, P, Q);
  topk_kernel<<<NB * MA, 256, 0, stream>>>(z, r, a1, a2, ba, attw, idxw);
  mlp_kernel<<<2 * NB * MA, 256, 0, stream>>>(r, P, Q, bp1, Wp2, bp2, attw, idxw, out);
}